// Round 15
// baseline (365.460 us; speedup 1.0000x reference)
//
#include <hip/hip_runtime.h>
#include <math.h>

#define HID 128
#define NSTEPS 64
#define SLEN 65
#define THREADS 256
#define ROWS 64       // per WG (2 pipelined tiles of 32)
#define TROWS 32
#define ASTRIDE 136   // 128 + 8 f16 pad, 16B aligned rows
#define FSTRIDE 40    // 32 + 8 f16 pad
#define DSTR 68       // 64 + 4 f32 pad, 16B-aligned rows for b128 flush reads

typedef _Float16 half8 __attribute__((ext_vector_type(8)));
typedef __fp16 fp16x2 __attribute__((ext_vector_type(2)));
typedef float floatx4 __attribute__((ext_vector_type(4)));

// R27 = R21 algebra + 2-tile software pipeline (ILP, not TLP).
// KEY REALIZATION: the "128-VGPR cliff" (R12/R13/R18 spills) was the
// launch_bounds(256,2) allocator cap, NOT hardware: at our pinned 8
// waves/CU (occupancy arm closed R15-R24), HW allows ~256 VGPR/wave
// (m69: waves/CU halves at 64/128/256). Dropping the min-waves arg lifts
// the cap with zero residency risk. That legalizes >128-reg designs.
// R27 USES IT: WG's 64 rows split into two independent 32-row tiles
// (batch rows are independent), pipelined 2 phases apart:
//   s0: A.G0(k)  | B.G23(k-1)      s1: A.G1(k)  | B.WF(k-1) | featRows0-31
//   s2: A.G23(k) | B.G0(k)         s3: A.WF(k)  | B.G1(k)   | featRows32-63
// Each slot = two INDEPENDENT dep-chains (separate acc sets aA*/aB*,
// separate buffers) -> ds_read->MFMA->EPI stalls of one stream fill under
// the other. Same MFMA count, same LDS bytes (cols/wave=32, traffic law),
// same 4 barriers/step, same per-row numerics as R21. Peak live ~160 reg.
// Schedule audit: every producer->consumer crosses >=1 barrier (verified
// per-buffer; features split s1/s3 land after the reading G0 of each tile).
// Drain: B.G23(63), B.WF(63) after the loop. setprio DROPPED (R26: -3%).
// Gates: VGPR_Count >128 (cap-lift proof) and <=256; WRITE == 8.19MB out,
// FETCH ~5.3MB (spill gate); conflicts ~3.4e7.
// CLOSED: cols/wave != 32 (traffic law); min-waves>2 (R15/R22 alloc law);
// XOR swizzle (R14); runtime-indexed frags (R20); <4 phases; tile/wave
// reshapes for occupancy (R23/R24); setprio (R26).
__global__ __launch_bounds__(THREADS)
void hedger(const float* __restrict__ S,
            const float* __restrict__ W0,  const float* __restrict__ b0,
            const float* __restrict__ rW1, const float* __restrict__ rb1,
            const float* __restrict__ rW2, const float* __restrict__ rb2,
            const float* __restrict__ sW1, const float* __restrict__ sb1,
            const float* __restrict__ sW2, const float* __restrict__ sb2,
            const float* __restrict__ Wf,  const float* __restrict__ bfp,
            float* __restrict__ out)
{
  __shared__ __align__(16) _Float16 bufA0[TROWS * ASTRIDE];  // t0 h0  8704 B
  __shared__ __align__(16) _Float16 bufB0[TROWS * ASTRIDE];  // t0 u   8704 B
  __shared__ __align__(16) _Float16 bufC0[TROWS * ASTRIDE];  // t0 v   8704 B
  __shared__ __align__(16) _Float16 bufA1[TROWS * ASTRIDE];  // t1 h0  8704 B
  __shared__ __align__(16) _Float16 bufB1[TROWS * ASTRIDE];  // t1 u   8704 B
  __shared__ __align__(16) _Float16 bufC1[TROWS * ASTRIDE];  // t1 v   8704 B
  __shared__ __align__(16) _Float16 featb[ROWS * FSTRIDE];   //        5120 B
  __shared__ __align__(16) _Float16 WfS[HID];                //         256 B
  __shared__ __align__(16) _Float16 WfuS[HID];               // rW2@Wf  256 B
  __shared__ __align__(16) _Float16 Ws2S[HID];               // sW2@Wf  256 B
  __shared__             float    CvalS;
  __shared__ __align__(16) float    deltab[ROWS * DSTR];     //       17408 B
  // total ~75.5 KB -> 2 WGs/CU (unchanged from R21)

  const int tid  = threadIdx.x;
  const int wave = tid >> 6;            // 0..3
  const int lane = tid & 63;
  const int l15  = lane & 15;
  const int quad = lane >> 4;
  const int r0 = blockIdx.x * ROWS;
  const int col0 = wave * 32 + 2 * l15; // lane's adjacent column pair

  // ---- persistent B fragments (96 VGPR): m=0 rW1, m=1 sW1, m=2 W25.
  half8 wfrag[3][4][2];  // [matrix][kIter][nt]
  {
    const float* Wm[2] = {rW1, sW1};
#pragma unroll
    for (int m = 0; m < 2; ++m)
#pragma unroll
      for (int kq = 0; kq < 4; ++kq)
#pragma unroll
        for (int nt = 0; nt < 2; ++nt) {
          const int n  = col0 + nt;
          const int kb = kq * 32 + quad * 8;
          half8 f;
#pragma unroll
          for (int j = 0; j < 8; ++j)
            f[j] = (_Float16)Wm[m][(kb + j) * HID + n];
          wfrag[m][kq][nt] = f;
        }
  }
  // W0 (8x128) zero-padded to K=32: only quad 0 (k<8) is real.
  half8 w0frag[2];
#pragma unroll
  for (int nt = 0; nt < 2; ++nt) {
    const int n = col0 + nt;
    half8 f;
#pragma unroll
    for (int j = 0; j < 8; ++j) {
      const int k = quad * 8 + j;
      f[j] = (k < 8) ? (_Float16)W0[k * HID + n] : (_Float16)0.f;
    }
    w0frag[nt] = f;
  }
  // biases: b0, rb1 direct; cvec = rb2@sW1 + sb1 via the lane's own sW1
  // fragments (quads partition k; shfl_xor 16/32 completes the dot).
  float b0r[2], rb1r[2], cv[2];
#pragma unroll
  for (int nt = 0; nt < 2; ++nt) {
    const int n = col0 + nt;
    b0r[nt] = b0[n]; rb1r[nt] = rb1[n];
    float p = 0.f;
#pragma unroll
    for (int kq = 0; kq < 4; ++kq) {
      const int kb = kq * 32 + quad * 8;
#pragma unroll
      for (int j = 0; j < 8; ++j)
        p += rb2[kb + j] * (float)wfrag[1][kq][nt][j];
    }
    p += __shfl_xor(p, 16);
    p += __shfl_xor(p, 32);
    cv[nt] = p + sb1[n];
  }

  // LDS init: featb zero-fill (pad cols 8..31 stay zero), Wf / wfu / ws2f
  // vectors, C scalar.
  for (int i = tid; i < ROWS * FSTRIDE; i += THREADS) featb[i] = (_Float16)0.f;
  if (tid < HID) {
    WfS[tid] = (_Float16)Wf[tid];
    float su = 0.f, ss = 0.f;
    for (int n = 0; n < HID; ++n) {
      su += rW2[tid * HID + n] * Wf[n];
      ss += sW2[tid * HID + n] * Wf[n];
    }
    WfuS[tid] = (_Float16)su;
    Ws2S[tid] = (_Float16)ss;
  }
  if (wave == 0) {   // C = (rb2 + sb2).Wf + bf
    float p = (rb2[lane] + sb2[lane]) * Wf[lane]
            + (rb2[lane + 64] + sb2[lane + 64]) * Wf[lane + 64];
    p += __shfl_xor(p, 1);  p += __shfl_xor(p, 2);  p += __shfl_xor(p, 4);
    p += __shfl_xor(p, 8);  p += __shfl_xor(p, 16); p += __shfl_xor(p, 32);
    if (lane == 0) CvalS = p + bfp[0];
  }

  // Two independent named acc sets -> the two per-slot streams interleave.
  floatx4 aA00, aA01, aA10, aA11;
  floatx4 aB00, aB01, aB10, aB11;

#define INIT_T(P, BR) do { \
  floatx4 z0 = {BR[0], BR[0], BR[0], BR[0]}; \
  floatx4 z1 = {BR[1], BR[1], BR[1], BR[1]}; \
  P##00 = z0; P##01 = z1; P##10 = z0; P##11 = z1; } while (0)

#define GEMM_T(P, SRC, MI) do { \
  _Pragma("unroll") for (int kq = 0; kq < 4; ++kq) { \
    const half8 af0 = *(const half8*)&SRC[(l15) * ASTRIDE + kq * 32 + quad * 8]; \
    const half8 af1 = *(const half8*)&SRC[(16 + l15) * ASTRIDE + kq * 32 + quad * 8]; \
    P##00 = __builtin_amdgcn_mfma_f32_16x16x32_f16(af0, wfrag[MI][kq][0], P##00, 0, 0, 0); \
    P##01 = __builtin_amdgcn_mfma_f32_16x16x32_f16(af0, wfrag[MI][kq][1], P##01, 0, 0, 0); \
    P##10 = __builtin_amdgcn_mfma_f32_16x16x32_f16(af1, wfrag[MI][kq][0], P##10, 0, 0, 0); \
    P##11 = __builtin_amdgcn_mfma_f32_16x16x32_f16(af1, wfrag[MI][kq][1], P##11, 0, 0, 0); \
  } } while (0)

#define EPI_LRELU_T(P, DST) do { \
  _Pragma("unroll") for (int r = 0; r < 4; ++r) { \
    const int rw0 = quad * 4 + r, rw1 = 16 + quad * 4 + r; \
    const float x0 = P##00[r], x1 = P##01[r]; \
    const float y0 = P##10[r], y1 = P##11[r]; \
    fp16x2 h0 = {(__fp16)fmaxf(x0, 0.2f * x0), (__fp16)fmaxf(x1, 0.2f * x1)}; \
    fp16x2 h1 = {(__fp16)fmaxf(y0, 0.2f * y0), (__fp16)fmaxf(y1, 0.2f * y1)}; \
    *(fp16x2*)&DST[rw0 * ASTRIDE + col0] = h0; \
    *(fp16x2*)&DST[rw1 * ASTRIDE + col0] = h1; \
  } } while (0)

#define EPI_STORE_T(P, DST) do { \
  _Pragma("unroll") for (int r = 0; r < 4; ++r) { \
    const int rw0 = quad * 4 + r, rw1 = 16 + quad * 4 + r; \
    fp16x2 h0 = {(__fp16)P##00[r], (__fp16)P##01[r]}; \
    fp16x2 h1 = {(__fp16)P##10[r], (__fp16)P##11[r]}; \
    *(fp16x2*)&DST[rw0 * ASTRIDE + col0] = h0; \
    *(fp16x2*)&DST[rw1 * ASTRIDE + col0] = h1; \
  } } while (0)

// G0 for tile with feature-row base TB into DST (K=32, w0frag; quads 1-3
// carry the K-pad zeros inside w0frag).
#define PH_G0(P, TB, DST) do { \
  INIT_T(P, b0r); \
  const half8 af0 = *(const half8*)&featb[(TB + l15) * FSTRIDE + quad * 8]; \
  const half8 af1 = *(const half8*)&featb[(TB + 16 + l15) * FSTRIDE + quad * 8]; \
  P##00 = __builtin_amdgcn_mfma_f32_16x16x32_f16(af0, w0frag[0], P##00, 0, 0, 0); \
  P##01 = __builtin_amdgcn_mfma_f32_16x16x32_f16(af0, w0frag[1], P##01, 0, 0, 0); \
  P##10 = __builtin_amdgcn_mfma_f32_16x16x32_f16(af1, w0frag[0], P##10, 0, 0, 0); \
  P##11 = __builtin_amdgcn_mfma_f32_16x16x32_f16(af1, w0frag[1], P##11, 0, 0, 0); \
  EPI_LRELU_T(P, DST); } while (0)

// WF for tile T (waves 2T,2T+1): delta = sigmoid(h0.Wf + u.wfu + v.ws2f + C)
#define PH_WF(T, BA, BB, BC, KK) do { \
  if ((wave >> 1) == (T)) { \
    floatx4 d1 = {0.f, 0.f, 0.f, 0.f}; \
    floatx4 d2 = {0.f, 0.f, 0.f, 0.f}; \
    floatx4 d3 = {0.f, 0.f, 0.f, 0.f}; \
    const int arow = ((wave & 1) * 16 + l15) * ASTRIDE; \
    _Pragma("unroll") for (int kq = 0; kq < 4; ++kq) { \
      const int off = kq * 32 + quad * 8; \
      const half8 a1 = *(const half8*)&BA[arow + off]; \
      const half8 w1 = *(const half8*)&WfS[off]; \
      d1 = __builtin_amdgcn_mfma_f32_16x16x32_f16(a1, w1, d1, 0, 0, 0); \
      const half8 a2 = *(const half8*)&BB[arow + off]; \
      const half8 w2 = *(const half8*)&WfuS[off]; \
      d2 = __builtin_amdgcn_mfma_f32_16x16x32_f16(a2, w2, d2, 0, 0, 0); \
      const half8 a3 = *(const half8*)&BC[arow + off]; \
      const half8 w3 = *(const half8*)&Ws2S[off]; \
      d3 = __builtin_amdgcn_mfma_f32_16x16x32_f16(a3, w3, d3, 0, 0, 0); \
    } \
    if (l15 < 4) { \
      const float s1 = (l15 & 2) ? ((l15 & 1) ? d1[3] : d1[2]) \
                                 : ((l15 & 1) ? d1[1] : d1[0]); \
      const float s2 = (l15 & 2) ? ((l15 & 1) ? d2[3] : d2[2]) \
                                 : ((l15 & 1) ? d2[1] : d2[0]); \
      const float s3 = (l15 & 2) ? ((l15 & 1) ? d3[3] : d3[2]) \
                                 : ((l15 & 1) ? d3[1] : d3[0]); \
      const int row = (T) * 32 + (wave & 1) * 16 + quad * 4 + l15; \
      const float d = 1.f / (1.f + expf(-(s1 + s2 + s3 + Cval))); \
      featb[row * FSTRIDE + 3] = (_Float16)d; \
      deltab[row * DSTR + (KK)] = d; \
    } \
  } } while (0)

// delta-independent features of step KK for this thread's row (lane<16).
#define PH_FEAT(KK) do { \
  const float lm = logf(Srow[KK] * 0.01f); \
  const float rr = lm - lm_prev; qv += rr * rr; \
  lm_prev = lm; cum_x += lm; \
  const float tT = (float)(KK) * (1.f / 64.f); \
  _Float16* fr = &featb[frow * FSTRIDE]; \
  fr[0] = (_Float16)lm; \
  fr[1] = (_Float16)(1.f - tT); \
  fr[4] = (_Float16)(cum_x / (float)((KK) + 1)); \
  fr[5] = (_Float16)qv; \
  fr[6] = (_Float16)(1.9f * sqrtf(qv + 1e-12f)); \
  fr[7] = (_Float16)tT; } while (0)

  // ---- init-time W25 = rW2 @ sW1: 4 FULLY-UNROLLED passes over 32-row
  // stages (rule #20: wfrag[2][p] indices compile-time). Pass p stages rW2
  // rows [32p,32p+32) into bufA0, GEMMs vs sW1 frags, gathers kq=p frag.
#pragma unroll
  for (int p = 0; p < 4; ++p) {
    __syncthreads();                       // bufA0/bufB0 free (covers featb fill)
    for (int i = tid; i < TROWS * HID; i += THREADS) {
      const int row = i >> 7, c = i & 127;
      bufA0[row * ASTRIDE + c] = (_Float16)rW2[(p * 32 + row) * HID + c];
    }
    __syncthreads();
    {
      float zr[2] = {0.f, 0.f};
      INIT_T(aA, zr);
      GEMM_T(aA, bufA0, 1);
      EPI_STORE_T(aA, bufB0);
    }
    __syncthreads();
    {
      half8 f0, f1;
#pragma unroll
      for (int j = 0; j < 8; ++j) {
        const int kl = quad * 8 + j;       // 0..31 within this pass
        const fp16x2 pr = *(const fp16x2*)&bufB0[kl * ASTRIDE + col0];
        f0[j] = (_Float16)pr[0];
        f1[j] = (_Float16)pr[1];
      }
      wfrag[2][p][0] = f0;
      wfrag[2][p][1] = f1;
    }
  }
  __syncthreads();   // gathers done; buffers return to loop use

  // step-0 features: lane<16, row = wave*16 + l15 (covers 0..63).
  const int frow = wave * 16 + l15;
  float lm_prev = 0.f, cum_x = 0.f, qv = 0.f;
  const float* Srow = S + (size_t)(r0 + frow) * SLEN;
  if (lane < 16) {
    const float lm = logf(Srow[0] * 0.01f);
    lm_prev = lm; cum_x = lm; qv = 0.f;
    _Float16* fr = &featb[frow * FSTRIDE];
    fr[0] = (_Float16)lm;
    fr[1] = (_Float16)1.0f;
    fr[2] = (_Float16)0.235f;
    fr[3] = (_Float16)0.f;                 // delta_0 = 0
    fr[4] = (_Float16)lm;                  // run_mean at k=0
    fr[5] = (_Float16)0.f;
    fr[6] = (_Float16)(1.9f * sqrtf(1e-12f));
    fr[7] = (_Float16)0.f;
  }
  __syncthreads();
  const float Cval = CvalS;

#pragma unroll 1
  for (int k = 0; k < NSTEPS; ++k) {
    // s0: A.G0(k) | B.G23(k-1)
    PH_G0(aA, 0, bufA0);
    if (k > 0) {
      INIT_T(aB, cv);
      GEMM_T(aB, bufA1, 1);
      GEMM_T(aB, bufB1, 2);
      EPI_LRELU_T(aB, bufC1);
    }
    __syncthreads();                                   // bar s0

    // s1: A.G1(k) | B.WF(k-1) | features(k+1) rows 0-31
    INIT_T(aA, rb1r);
    GEMM_T(aA, bufA0, 0);
    EPI_LRELU_T(aA, bufB0);
    if (k > 0) PH_WF(1, bufA1, bufB1, bufC1, k - 1);
    if (wave < 2 && lane < 16) PH_FEAT(k + 1);         // after A.G0(k) read (s0)
    __syncthreads();                                   // bar s1

    // s2: A.G23(k) | B.G0(k)
    INIT_T(aA, cv);
    GEMM_T(aA, bufA0, 1);
    GEMM_T(aA, bufB0, 2);
    EPI_LRELU_T(aA, bufC0);
    PH_G0(aB, 32, bufA1);
    __syncthreads();                                   // bar s2

    // s3: A.WF(k) | B.G1(k) | features(k+1) rows 32-63
    PH_WF(0, bufA0, bufB0, bufC0, k);
    INIT_T(aB, rb1r);
    GEMM_T(aB, bufA1, 0);
    EPI_LRELU_T(aB, bufB1);
    if (wave >= 2 && lane < 16) PH_FEAT(k + 1);        // after B.G0(k) read (s2)
    __syncthreads();                                   // bar s3
  }

  // drain tile B's final step
  {
    INIT_T(aB, cv);
    GEMM_T(aB, bufA1, 1);
    GEMM_T(aB, bufB1, 2);
    EPI_LRELU_T(aB, bufC1);
  }
  __syncthreads();
  PH_WF(1, bufA1, bufB1, bufC1, NSTEPS - 1);
  __syncthreads();                                     // deltab visible

  // coalesced output flush: 64 rows x 64 steps, dwordx4 stores.
  {
    const int row = tid >> 2;                // 0..63
    const int c0  = (tid & 3) * 16;          // 0,16,32,48
    const float* dr = &deltab[row * DSTR + c0];
    float* orow = &out[(size_t)(r0 + row) * NSTEPS + c0];
#pragma unroll
    for (int u = 0; u < 4; ++u) {
      const floatx4 v = *(const floatx4*)&dr[u * 4];
      *(floatx4*)&orow[u * 4] = v;
    }
  }
#undef INIT_T
#undef GEMM_T
#undef EPI_LRELU_T
#undef EPI_STORE_T
#undef PH_G0
#undef PH_WF
#undef PH_FEAT
}

extern "C" void kernel_launch(void* const* d_in, const int* in_sizes, int n_in,
                              void* d_out, int out_size, void* d_ws, size_t ws_size,
                              hipStream_t stream) {
  const float* S   = (const float*)d_in[0];
  const float* W0  = (const float*)d_in[1];
  const float* b0  = (const float*)d_in[2];
  const float* rW1 = (const float*)d_in[3];
  const float* rb1 = (const float*)d_in[4];
  const float* rW2 = (const float*)d_in[5];
  const float* rb2 = (const float*)d_in[6];
  const float* sW1 = (const float*)d_in[7];
  const float* sb1 = (const float*)d_in[8];
  const float* sW2 = (const float*)d_in[9];
  const float* sb2 = (const float*)d_in[10];
  const float* Wf  = (const float*)d_in[11];
  const float* bf  = (const float*)d_in[12];
  float* out = (float*)d_out;

  const int B = out_size / NSTEPS;        // 32768
  const int nblocks = B / ROWS;           // 512 WGs -> 2 per CU
  hedger<<<nblocks, THREADS, 0, stream>>>(
      S, W0, b0, rW1, rb1, rW2, rb2, sW1, sb1, sW2, sb2, Wf, bf, out);
}

// Round 16
// 341.596 us; speedup vs baseline: 1.0699x; 1.0699x over previous
//
#include <hip/hip_runtime.h>
#include <math.h>

#define HID 128
#define NSTEPS 64
#define SLEN 65
#define THREADS 256
#define ROWS 64
#define ASTRIDE 136   // 128 + 8 f16 pad, 16B aligned rows
#define FSTRIDE 40    // 32 + 8 f16 pad
#define DSTR 68       // 64 + 4 f32 pad, 16B-aligned rows for b128 flush reads

typedef _Float16 half8 __attribute__((ext_vector_type(8)));
typedef __fp16 fp16x2 __attribute__((ext_vector_type(2)));
typedef float floatx4 __attribute__((ext_vector_type(4)));

// R28 = R21 verbatim restore (session best: 309us steady / 340us e2e).
// FINAL STATE after 15 rounds. R21 is a verified local optimum; seven
// consecutive deviations regressed:
//   R22 spill (launch_bounds min-waves>2 collapses alloc target to 64),
//   R23 smaller tile (+21%), R24 8-wave M-split (+19%), R26 setprio+
//   straggler-balance (+3%), R27 dual-tile ILP pipeline (+10%, remat
//   VALU at the 128 cap).
// CLOSED ARMS (evidence):
//  - Occupancy: pinned 8 waves/CU (2/SIMD) under every legal geometry
//    (R15/R16/R17/R22/R23/R24). TLP is not available.
//  - Phases: 4 = algorithmic minimum; algebraic deletions captured:
//    G4 (R19: h2.Wf distributed via ws2f=sW2@Wf) and G2 (R21: W25=rW2@sW1
//    folded, v = lrelu(h0@sW1 + u@W25 + cvec)). 6->5 phases gave -17%,
//    5->4 gave -2% (diminishing).
//  - LDS: cols/wave=32 is the traffic optimum (bytes ~ 128/colsPerWave,
//    R16/R17/R24); SQ_LDS_BANK_CONFLICT 3.4e7 is structural b128
//    serialization, layout-invariant (R14).
//  - Registers: 120/128; any cross-barrier state (+8..+32) remats/spills
//    (R18, R27). Runtime-indexed frag arrays -> scratch (R20, rule #20).
//  - Scheduling: compiler's natural schedule beats setprio (R26) and
//    source-level ILP pipelining (R27).
// Residue: barrier-synchronized dependency latency at 2 waves/SIMD; no
// pipe >50% (MfmaUtil 36, VALUBusy 42, LDS ~53% incl conflicts). The
// chain featb->h0->u->v->delta x64 steps with LDS round-trip + barrier
// per stage is the structural floor for this formulation.
// Spill gate for any future edit: WRITE_SIZE == 8.192MB (out only),
// FETCH ~5.3MB, VGPR_Count ~120.
__global__ __launch_bounds__(THREADS, 2)
void hedger(const float* __restrict__ S,
            const float* __restrict__ W0,  const float* __restrict__ b0,
            const float* __restrict__ rW1, const float* __restrict__ rb1,
            const float* __restrict__ rW2, const float* __restrict__ rb2,
            const float* __restrict__ sW1, const float* __restrict__ sb1,
            const float* __restrict__ sW2, const float* __restrict__ sb2,
            const float* __restrict__ Wf,  const float* __restrict__ bfp,
            float* __restrict__ out)
{
  __shared__ __align__(16) _Float16 bufA[ROWS * ASTRIDE];   // h0   17408 B
  __shared__ __align__(16) _Float16 bufB[ROWS * ASTRIDE];   // u    17408 B
  __shared__ __align__(16) _Float16 bufC[ROWS * ASTRIDE];   // v    17408 B
  __shared__ __align__(16) _Float16 featb[ROWS * FSTRIDE];  //       5120 B
  __shared__ __align__(16) _Float16 WfS[HID];               //        256 B
  __shared__ __align__(16) _Float16 WfuS[HID];              // rW2@Wf 256 B
  __shared__ __align__(16) _Float16 Ws2S[HID];              // sW2@Wf 256 B
  __shared__             float    CvalS;
  __shared__ __align__(16) float    deltab[ROWS * DSTR];    //      17408 B
  // total ~75.5 KB -> 2 WGs/CU

  const int tid  = threadIdx.x;
  const int wave = tid >> 6;            // 0..3
  const int lane = tid & 63;
  const int l15  = lane & 15;
  const int quad = lane >> 4;
  const int n_base = wave * 32;
  const int r0 = blockIdx.x * ROWS;
  const int col0 = n_base + 2 * l15;    // lane's adjacent column pair

  // ---- persistent B fragments (96 VGPR): m=0 rW1, m=1 sW1, m=2 W25.
  half8 wfrag[3][4][2];  // [matrix][kIter][nt]
  {
    const float* Wm[2] = {rW1, sW1};
#pragma unroll
    for (int m = 0; m < 2; ++m)
#pragma unroll
      for (int kq = 0; kq < 4; ++kq)
#pragma unroll
        for (int nt = 0; nt < 2; ++nt) {
          const int n  = col0 + nt;
          const int kb = kq * 32 + quad * 8;
          half8 f;
#pragma unroll
          for (int j = 0; j < 8; ++j)
            f[j] = (_Float16)Wm[m][(kb + j) * HID + n];
          wfrag[m][kq][nt] = f;
        }
  }
  // W0 (8x128) zero-padded to K=32: only quad 0 (k<8) is real.
  half8 w0frag[2];
#pragma unroll
  for (int nt = 0; nt < 2; ++nt) {
    const int n = col0 + nt;
    half8 f;
#pragma unroll
    for (int j = 0; j < 8; ++j) {
      const int k = quad * 8 + j;
      f[j] = (k < 8) ? (_Float16)W0[k * HID + n] : (_Float16)0.f;
    }
    w0frag[nt] = f;
  }
  // biases: b0, rb1 direct; cvec = rb2@sW1 + sb1 via the lane's own sW1
  // fragments (quads partition k; shfl_xor 16/32 completes the dot).
  float b0r[2], rb1r[2], cv[2];
#pragma unroll
  for (int nt = 0; nt < 2; ++nt) {
    const int n = col0 + nt;
    b0r[nt] = b0[n]; rb1r[nt] = rb1[n];
    float p = 0.f;
#pragma unroll
    for (int kq = 0; kq < 4; ++kq) {
      const int kb = kq * 32 + quad * 8;
#pragma unroll
      for (int j = 0; j < 8; ++j)
        p += rb2[kb + j] * (float)wfrag[1][kq][nt][j];
    }
    p += __shfl_xor(p, 16);
    p += __shfl_xor(p, 32);
    cv[nt] = p + sb1[n];
  }

  // LDS init: featb zero-fill (pad cols 8..31 stay zero), Wf / wfu / ws2f
  // vectors, C scalar.
  for (int i = tid; i < ROWS * FSTRIDE; i += THREADS) featb[i] = (_Float16)0.f;
  if (tid < HID) {
    WfS[tid] = (_Float16)Wf[tid];
    float su = 0.f, ss = 0.f;
    for (int n = 0; n < HID; ++n) {
      su += rW2[tid * HID + n] * Wf[n];
      ss += sW2[tid * HID + n] * Wf[n];
    }
    WfuS[tid] = (_Float16)su;
    Ws2S[tid] = (_Float16)ss;
  }
  if (wave == 0) {   // C = (rb2 + sb2).Wf + bf
    float p = (rb2[lane] + sb2[lane]) * Wf[lane]
            + (rb2[lane + 64] + sb2[lane + 64]) * Wf[lane + 64];
    p += __shfl_xor(p, 1);  p += __shfl_xor(p, 2);  p += __shfl_xor(p, 4);
    p += __shfl_xor(p, 8);  p += __shfl_xor(p, 16); p += __shfl_xor(p, 32);
    if (lane == 0) CvalS = p + bfp[0];
  }

  floatx4 acc[4][2];

#define INIT_BIAS(BR) do { \
  _Pragma("unroll") for (int mt = 0; mt < 4; ++mt) \
  _Pragma("unroll") for (int nt = 0; nt < 2; ++nt) { \
    floatx4 z = {BR[nt], BR[nt], BR[nt], BR[nt]}; acc[mt][nt] = z; } } while (0)

#define GEMM128(SRC, MI) do { \
  _Pragma("unroll") for (int kq = 0; kq < 4; ++kq) { \
    half8 afr[4]; \
    _Pragma("unroll") for (int mt = 0; mt < 4; ++mt) \
      afr[mt] = *(const half8*)&SRC[(mt * 16 + l15) * ASTRIDE + kq * 32 + quad * 8]; \
    _Pragma("unroll") for (int mt = 0; mt < 4; ++mt) \
    _Pragma("unroll") for (int nt = 0; nt < 2; ++nt) \
      acc[mt][nt] = __builtin_amdgcn_mfma_f32_16x16x32_f16( \
          afr[mt], wfrag[MI][kq][nt], acc[mt][nt], 0, 0, 0); \
  } } while (0)

#define EPI_LRELU(DST) do { \
  _Pragma("unroll") for (int mt = 0; mt < 4; ++mt) \
  _Pragma("unroll") for (int r = 0; r < 4; ++r) { \
    const int row = mt * 16 + quad * 4 + r; \
    const float v0 = acc[mt][0][r]; \
    const float v1 = acc[mt][1][r]; \
    fp16x2 h2 = {(__fp16)fmaxf(v0, 0.2f * v0), (__fp16)fmaxf(v1, 0.2f * v1)}; \
    *(fp16x2*)&DST[row * ASTRIDE + col0] = h2; \
  } } while (0)

#define EPI_STORE(DST) do { \
  _Pragma("unroll") for (int mt = 0; mt < 4; ++mt) \
  _Pragma("unroll") for (int r = 0; r < 4; ++r) { \
    const int row = mt * 16 + quad * 4 + r; \
    fp16x2 h2 = {(__fp16)acc[mt][0][r], (__fp16)acc[mt][1][r]}; \
    *(fp16x2*)&DST[row * ASTRIDE + col0] = h2; \
  } } while (0)

  // ---- init-time W25 = rW2 @ sW1 via the GEMM machinery (2 half passes).
  // FULLY UNROLLED over h (rule #20): every wfrag[2][kq][nt] index below is
  // a compile-time constant, keeping wfrag in VGPRs.
#pragma unroll
  for (int h = 0; h < 2; ++h) {
    __syncthreads();                       // bufA/bufB free (also covers featb fill)
    for (int i = tid; i < ROWS * HID; i += THREADS) {
      const int row = i >> 7, c = i & 127;
      bufA[row * ASTRIDE + c] = (_Float16)rW2[(h * 64 + row) * HID + c];
    }
    __syncthreads();
    {
      float zr[2] = {0.f, 0.f};
      INIT_BIAS(zr);
      GEMM128(bufA, 1);
      EPI_STORE(bufB);
    }
    __syncthreads();
#pragma unroll
    for (int kqh = 0; kqh < 2; ++kqh) {
      const int kq = h * 2 + kqh;          // compile-time (h, kqh unrolled)
      half8 f0, f1;
#pragma unroll
      for (int j = 0; j < 8; ++j) {
        const int kl = kq * 32 + quad * 8 + j - h * 64;   // 0..63
        const fp16x2 p = *(const fp16x2*)&bufB[kl * ASTRIDE + col0];
        f0[j] = (_Float16)p[0];
        f1[j] = (_Float16)p[1];
      }
      wfrag[2][kq][0] = f0;
      wfrag[2][kq][1] = f1;
    }
  }
  __syncthreads();   // gathers done; bufA/bufB return to loop use

  // step-0 features (threads 0..63 each own one row; S read from global)
  float lm_prev = 0.f, cum_x = 0.f, qv = 0.f;
  const float* Srow = S + (size_t)(r0 + (tid & (ROWS - 1))) * SLEN;
  if (tid < ROWS) {
    const float lm = logf(Srow[0] * 0.01f);
    lm_prev = lm; cum_x = lm; qv = 0.f;
    _Float16* fr = &featb[tid * FSTRIDE];
    fr[0] = (_Float16)lm;
    fr[1] = (_Float16)1.0f;
    fr[2] = (_Float16)0.235f;
    fr[3] = (_Float16)0.f;                 // delta_0 = 0
    fr[4] = (_Float16)lm;                  // run_mean at k=0
    fr[5] = (_Float16)0.f;
    fr[6] = (_Float16)(1.9f * sqrtf(1e-12f));
    fr[7] = (_Float16)0.f;
  }
  __syncthreads();
  const float Cval = CvalS;

#pragma unroll 1
  for (int k = 0; k < NSTEPS; ++k) {
    // G0: h0 = lrelu(featPad @ W0pad + b0)
    INIT_BIAS(b0r);
    {
      half8 afr[4];
#pragma unroll
      for (int mt = 0; mt < 4; ++mt)
        afr[mt] = *(const half8*)&featb[(mt * 16 + l15) * FSTRIDE + quad * 8];
#pragma unroll
      for (int mt = 0; mt < 4; ++mt)
#pragma unroll
        for (int nt = 0; nt < 2; ++nt)
          acc[mt][nt] = __builtin_amdgcn_mfma_f32_16x16x32_f16(
              afr[mt], w0frag[nt], acc[mt][nt], 0, 0, 0);
    }
    EPI_LRELU(bufA);
    __syncthreads();                                   // bar A: h0 in bufA

    // delta-independent features of step k+1 — overlaps G1.
    // (Srow[k+1] valid at k=63: SLEN=65; write is dead then, harmless.)
    if (tid < ROWS) {
      const int kk = k + 1;
      const float lm = logf(Srow[kk] * 0.01f);
      const float rr = lm - lm_prev; qv += rr * rr;
      lm_prev = lm; cum_x += lm;
      const float tT = (float)kk * (1.f / 64.f);
      _Float16* fr = &featb[tid * FSTRIDE];
      fr[0] = (_Float16)lm;
      fr[1] = (_Float16)(1.f - tT);
      fr[4] = (_Float16)(cum_x / (float)(kk + 1));
      fr[5] = (_Float16)qv;
      fr[6] = (_Float16)(1.9f * sqrtf(qv + 1e-12f));
      fr[7] = (_Float16)tT;
    }

    // G1: u = lrelu(h0 @ rW1 + rb1)
    INIT_BIAS(rb1r);  GEMM128(bufA, 0);  EPI_LRELU(bufB);
    __syncthreads();                                   // bar B: u in bufB

    // G23: v = lrelu(h0 @ sW1 + u @ W25 + cvec)   (G2 deleted)
    INIT_BIAS(cv);
    GEMM128(bufA, 1);
    GEMM128(bufB, 2);
    EPI_LRELU(bufC);
    __syncthreads();                                   // bar C: v in bufC

    // WF: delta = sigmoid(h0.Wf + u.wfu + v.ws2f + C), three independent
    // broadcast-B MFMA chains; no cross-barrier register liveness.
    {
      floatx4 d1 = {0.f, 0.f, 0.f, 0.f};
      floatx4 d2 = {0.f, 0.f, 0.f, 0.f};
      floatx4 d3 = {0.f, 0.f, 0.f, 0.f};
      const int arow = (wave * 16 + l15) * ASTRIDE;
#pragma unroll
      for (int kq = 0; kq < 4; ++kq) {
        const int off = kq * 32 + quad * 8;
        const half8 a1 = *(const half8*)&bufA[arow + off];
        const half8 w1 = *(const half8*)&WfS[off];
        d1 = __builtin_amdgcn_mfma_f32_16x16x32_f16(a1, w1, d1, 0, 0, 0);
        const half8 a2 = *(const half8*)&bufB[arow + off];
        const half8 w2 = *(const half8*)&WfuS[off];
        d2 = __builtin_amdgcn_mfma_f32_16x16x32_f16(a2, w2, d2, 0, 0, 0);
        const half8 a3 = *(const half8*)&bufC[arow + off];
        const half8 w3 = *(const half8*)&Ws2S[off];
        d3 = __builtin_amdgcn_mfma_f32_16x16x32_f16(a3, w3, d3, 0, 0, 0);
      }
      if (l15 < 4) {
        // static-index select (rule: no runtime vector index)
        const float s1 = (l15 & 2) ? ((l15 & 1) ? d1[3] : d1[2])
                                   : ((l15 & 1) ? d1[1] : d1[0]);
        const float s2 = (l15 & 2) ? ((l15 & 1) ? d2[3] : d2[2])
                                   : ((l15 & 1) ? d2[1] : d2[0]);
        const float s3 = (l15 & 2) ? ((l15 & 1) ? d3[3] : d3[2])
                                   : ((l15 & 1) ? d3[1] : d3[0]);
        const int row = wave * 16 + quad * 4 + l15;
        const float d = 1.f / (1.f + expf(-(s1 + s2 + s3 + Cval)));
        featb[row * FSTRIDE + 3] = (_Float16)d;        // fr[3] for step k+1
        deltab[row * DSTR + k] = d;                    // staged output
      }
    }
    __syncthreads();                                   // bar D: featb complete
  }

  // coalesced output flush: 64 rows x 64 steps, dwordx4 stores.
  {
    const int row = tid >> 2;                // 0..63
    const int c0  = (tid & 3) * 16;          // 0,16,32,48
    const float* dr = &deltab[row * DSTR + c0];
    float* orow = &out[(size_t)(r0 + row) * NSTEPS + c0];
#pragma unroll
    for (int u = 0; u < 4; ++u) {
      const floatx4 v = *(const floatx4*)&dr[u * 4];
      *(floatx4*)&orow[u * 4] = v;
    }
  }
#undef INIT_BIAS
#undef GEMM128
#undef EPI_LRELU
#undef EPI_STORE
}

extern "C" void kernel_launch(void* const* d_in, const int* in_sizes, int n_in,
                              void* d_out, int out_size, void* d_ws, size_t ws_size,
                              hipStream_t stream) {
  const float* S   = (const float*)d_in[0];
  const float* W0  = (const float*)d_in[1];
  const float* b0  = (const float*)d_in[2];
  const float* rW1 = (const float*)d_in[3];
  const float* rb1 = (const float*)d_in[4];
  const float* rW2 = (const float*)d_in[5];
  const float* rb2 = (const float*)d_in[6];
  const float* sW1 = (const float*)d_in[7];
  const float* sb1 = (const float*)d_in[8];
  const float* sW2 = (const float*)d_in[9];
  const float* sb2 = (const float*)d_in[10];
  const float* Wf  = (const float*)d_in[11];
  const float* bf  = (const float*)d_in[12];
  float* out = (float*)d_out;

  const int B = out_size / NSTEPS;        // 32768
  const int nblocks = B / ROWS;           // 512 WGs -> 2 per CU
  hedger<<<nblocks, THREADS, 0, stream>>>(
      S, W0, b0, rW1, rb1, rW2, rb2, sW1, sb1, sW2, sb2, Wf, bf, out);
}